// Round 8
// baseline (232.879 us; speedup 1.0000x reference)
//
#include <hip/hip_runtime.h>
#include <hip/hip_bf16.h>
#include <math.h>

#define N_NODES 100000
#define N_EDGES 1600000
#define D_FEAT 32
#define D_HID 64
#define D_OUT 64
#define CAP 48          // per-node slot capacity; deg ~ Poisson(16), safe
#define NPB 64          // nodes per agg block (1<<6)
#define NSB 1563        // ceil(100000/64) agg blocks
#define BKT_NODES 256   // nodes per coarse bucket (1<<8)
#define NBKT 391        // ceil(100000/256)
#define ECAP 4608       // edge capacity per coarse bucket (mean 4092, +8 sigma)
#define B1 200          // binning blocks
#define E_PER_B1 8000   // 200 * 8000 = 1.6M edges exactly (div by 4)
#define NB_NODE 1024    // node-precompute blocks

typedef short bf16x8 __attribute__((ext_vector_type(8)));
typedef float f32x4  __attribute__((ext_vector_type(4)));

__device__ inline unsigned short f2bf(float f) {   // RNE f32 -> bf16
    unsigned u = __float_as_uint(f);
    u += 0x7fff + ((u >> 16) & 1);
    return (unsigned short)(u >> 16);
}
__device__ inline float bf2f(unsigned short h) {
    return __uint_as_float(((unsigned)h) << 16);
}
__device__ inline unsigned pack2bf(float lo, float hi) {   // -> [hi|lo] u32
    return ((unsigned)f2bf(hi) << 16) | (unsigned)f2bf(lo);
}

union afu { uint4 u; bf16x8 v; };

// One A-fragment (8 bf16) from a packed vb row chunk and f32 q chunk:
// af[2m]   = relu(bf2f(lo16(w_m)) - qk[2m]);  af[2m+1] = relu(hi16 - qk[2m+1])
__device__ inline afu abuild(uint4 vv, const float* qk) {
    afu af;
#pragma unroll
    for (int m = 0; m < 4; ++m) {
        unsigned w = (&vv.x)[m];
        float flo = __uint_as_float(w << 16);
        float fhi = __uint_as_float(w & 0xFFFF0000u);
        float hlo = fmaxf(flo - qk[2 * m],     0.0f);
        float hhi = fmaxf(fhi - qk[2 * m + 1], 0.0f);
        (&af.u.x)[m] = pack2bf(hlo, hhi);
    }
    return af;
}

// ---------------------------------------------------------------------------
// Kernel 1: per-node precompute (f32 math, bf16 store)
//   q[n][k] = pos[n] @ W1[32:35];  v[n][k] = b1[k] + x[n] @ W1[:32] + q[n][k]
// per-edge layer-1 output = relu(v[src] - q[dst]).
// ---------------------------------------------------------------------------
__global__ __launch_bounds__(256)
void node_kernel(const float* __restrict__ x,
                 const float* __restrict__ pos,
                 const float* __restrict__ W1,
                 const float* __restrict__ b1,
                 unsigned short* __restrict__ vb,
                 unsigned short* __restrict__ qb) {
    const int lane = threadIdx.x & 63;
    const int wid  = (blockIdx.x * blockDim.x + threadIdx.x) >> 6;
    const int nw   = (NB_NODE * 256) >> 6;

    float w[D_FEAT + 3];
#pragma unroll
    for (int f = 0; f < D_FEAT + 3; ++f)
        w[f] = W1[f * D_HID + lane];
    const float bb = b1[lane];

    for (int node = wid; node < N_NODES; node += nw) {
        const float* xr = x + (size_t)node * D_FEAT;
        float acc = bb;
#pragma unroll
        for (int f = 0; f < D_FEAT; ++f)
            acc = fmaf(xr[f], w[f], acc);

        const float* pr = pos + (size_t)node * 3;
        float qa = 0.0f;
#pragma unroll
        for (int p = 0; p < 3; ++p)
            qa = fmaf(pr[p], w[D_FEAT + p], qa);

        vb[(size_t)node * D_HID + lane] = f2bf(acc + qa);
        qb[(size_t)node * D_HID + lane] = f2bf(qa);
    }
}

// ---------------------------------------------------------------------------
// Kernel 2: two-phase binning into 391 coarse buckets of 256 dst-nodes.
// Bigger buckets => ~20 appends per block-bucket = full 64B lines (dense
// writes; the old 64-node buckets left ~5 entries/line from 4 interleaved
// blocks). Per block: LDS histogram -> one global atomicAdd per bucket
// reserving a contiguous range -> placement via LDS cursors.
// Entry packing: (src << 8) | (dst & 255)  (17+8 bits < 32).
// ---------------------------------------------------------------------------
__global__ __launch_bounds__(1024)
void bin_kernel(const int* __restrict__ src,
                const int* __restrict__ dst,
                int* __restrict__ gcnt,
                unsigned int* __restrict__ coarse) {
    __shared__ int hist[NBKT];
    const int tid = threadIdx.x;
    const int e0 = blockIdx.x * E_PER_B1;
    const int nq = E_PER_B1 / 4;            // 2000 int4 per block

    for (int b = tid; b < NBKT; b += 1024) hist[b] = 0;
    __syncthreads();

    const int4* d4p = (const int4*)(dst + e0);
    const int4* s4p = (const int4*)(src + e0);

    for (int i = tid; i < nq; i += 1024) {
        int4 d4 = d4p[i];
        atomicAdd(&hist[d4.x >> 8], 1);
        atomicAdd(&hist[d4.y >> 8], 1);
        atomicAdd(&hist[d4.z >> 8], 1);
        atomicAdd(&hist[d4.w >> 8], 1);
    }
    __syncthreads();

    for (int b = tid; b < NBKT; b += 1024) {
        int c = hist[b];
        hist[b] = (c > 0) ? atomicAdd(&gcnt[b], c) : 0;
    }
    __syncthreads();

    for (int i = tid; i < nq; i += 1024) {
        int4 d4 = d4p[i];
        int4 s4 = s4p[i];
        int p0 = atomicAdd(&hist[d4.x >> 8], 1);
        int p1 = atomicAdd(&hist[d4.y >> 8], 1);
        int p2 = atomicAdd(&hist[d4.z >> 8], 1);
        int p3 = atomicAdd(&hist[d4.w >> 8], 1);
        if (p0 < ECAP) coarse[(size_t)(d4.x >> 8) * ECAP + p0] = ((unsigned)s4.x << 8) | (unsigned)(d4.x & 255);
        if (p1 < ECAP) coarse[(size_t)(d4.y >> 8) * ECAP + p1] = ((unsigned)s4.y << 8) | (unsigned)(d4.y & 255);
        if (p2 < ECAP) coarse[(size_t)(d4.z >> 8) * ECAP + p2] = ((unsigned)s4.z << 8) | (unsigned)(d4.z & 255);
        if (p3 < ECAP) coarse[(size_t)(d4.w >> 8) * ECAP + p3] = ((unsigned)s4.w << 8) | (unsigned)(d4.w & 255);
    }
}

// ---------------------------------------------------------------------------
// Kernel 3: fused fine-bucketing + per-node MFMA aggregation.
// Block sb covers 64 nodes = quarter (sb&3) of coarse bucket (sb>>2); it
// scans the bucket's dense edge list and keeps its quarter (4x read of a
// small L2-resident list trades for bin's dense writes). Then each of 4
// waves aggregates 16 nodes: A[m][k] = relu(v[src_m][k] - q[i][k]), layer-2
// via 4x2 mfma_f32_16x16x32_bf16 per 16-row batch (sequential batches, slot
// prefetched one batch ahead), register max, one coalesced store.
// Padding rows use src=node (self-loop, idempotent under max).
// ---------------------------------------------------------------------------
__global__ __launch_bounds__(256)
void agg_kernel(const unsigned short* __restrict__ vb,
                const unsigned short* __restrict__ qb,
                const float* __restrict__ W2,
                const float* __restrict__ b2,
                const int* __restrict__ gcnt,
                const unsigned int* __restrict__ coarse,
                float* __restrict__ out) {
    __shared__ int lcnt[NPB];
    __shared__ int lslots[NPB][CAP];

    const int tid  = threadIdx.x;
    const int lane = tid & 63;
    const int wave = tid >> 6;             // 0..3
    const int quad = lane >> 4;
    const int mrow = lane & 15;
    const int sb   = blockIdx.x;
    const int bkt  = sb >> 2;
    const int qsel = sb & 3;               // which 64-node quarter
    const int nbase = sb << 6;

    // B fragments: bfrag[t][kh][j] = W2[kh*32 + quad*8 + j][t*16 + mrow]
    bf16x8 bfrag[4][2];
#pragma unroll
    for (int t = 0; t < 4; ++t)
#pragma unroll
        for (int kh = 0; kh < 2; ++kh) {
            bf16x8 f;
#pragma unroll
            for (int j = 0; j < 8; ++j)
                f[j] = (short)f2bf(W2[(kh * 32 + quad * 8 + j) * D_OUT + t * 16 + mrow]);
            bfrag[t][kh] = f;
        }
    float bias[4];
#pragma unroll
    for (int t = 0; t < 4; ++t) bias[t] = b2[t * 16 + mrow];

    // fine bucketing into LDS: scan bucket's edge list, keep our quarter
    int E_b = gcnt[bkt];
    if (E_b > ECAP) E_b = ECAP;
    for (int i = tid; i < NPB; i += 256) lcnt[i] = 0;
    __syncthreads();
    const unsigned int* crow = coarse + (size_t)bkt * ECAP;
    for (int i = tid; i < E_b; i += 256) {
        unsigned enc = crow[i];
        int local = (int)(enc & 255u);
        if ((local >> 6) == qsel) {
            int ln = local & 63;
            int p = atomicAdd(&lcnt[ln], 1);
            if (p < CAP) lslots[ln][p] = (int)(enc >> 8);
        }
    }
    __syncthreads();

    // per-node aggregation, 16 nodes per wave, sequential batches + prefetch
    for (int ln = wave; ln < NPB; ln += 4) {
        const int node = nbase + ln;
        if (node >= N_NODES) break;

        float qf[2][8];
#pragma unroll
        for (int kh = 0; kh < 2; ++kh) {
            bf16x8 qv = *(const bf16x8*)(qb + (size_t)node * D_HID + kh * 32 + quad * 8);
#pragma unroll
            for (int j = 0; j < 8; ++j) qf[kh][j] = bf2f((unsigned short)qv[j]);
        }

        int deg = lcnt[ln];
        if (deg > CAP) deg = CAP;
        const int rows = deg + 1;              // + self-loop
        const int nbat = (rows + 15) >> 4;
        const int* lsl = lslots[ln];

        float rmax[4][4];
#pragma unroll
        for (int t = 0; t < 4; ++t)
#pragma unroll
            for (int r = 0; r < 4; ++r) rmax[t][r] = -INFINITY;

        const uint4* vbq = (const uint4*)vb;   // row = 8 uint4
        int s_cur = (mrow < deg) ? lsl[mrow] : node;
        for (int b = 0; b < nbat; ++b) {
            int idx = (b + 1) * 16 + mrow;
            int s_nxt = (idx < deg) ? lsl[idx] : node;   // prefetch next batch

            const uint4* pa = vbq + (size_t)s_cur * 8 + quad;
            uint4 v0 = pa[0], v1 = pa[4];      // kh=0 / kh=1 chunks

            afu a0 = abuild(v0, qf[0]);
            afu a1 = abuild(v1, qf[1]);

#pragma unroll
            for (int t = 0; t < 4; ++t) {
                f32x4 acc = (f32x4){0.f, 0.f, 0.f, 0.f};
                acc = __builtin_amdgcn_mfma_f32_16x16x32_bf16(a0.v, bfrag[t][0], acc, 0, 0, 0);
                acc = __builtin_amdgcn_mfma_f32_16x16x32_bf16(a1.v, bfrag[t][1], acc, 0, 0, 0);
#pragma unroll
                for (int r = 0; r < 4; ++r)
                    rmax[t][r] = fmaxf(rmax[t][r], acc[r]);
            }
            s_cur = s_nxt;
        }

        float fin[4];
#pragma unroll
        for (int t = 0; t < 4; ++t) {
            float m = fmaxf(fmaxf(rmax[t][0], rmax[t][1]), fmaxf(rmax[t][2], rmax[t][3]));
            m = fmaxf(m, __shfl_xor(m, 16, 64));
            m = fmaxf(m, __shfl_xor(m, 32, 64));
            fin[t] = m + bias[t];
        }
        float r = (quad == 0) ? fin[0] : (quad == 1) ? fin[1] : (quad == 2) ? fin[2] : fin[3];
        out[(size_t)node * D_OUT + lane] = r;
    }
}

// ---------------------------------------------------------------------------
extern "C" void kernel_launch(void* const* d_in, const int* in_sizes, int n_in,
                              void* d_out, int out_size, void* d_ws, size_t ws_size,
                              hipStream_t stream) {
    const float* x   = (const float*)d_in[0];
    const float* pos = (const float*)d_in[1];
    const int*   ei  = (const int*)d_in[2];   // [2][N_EDGES]: row0=src, row1=dst
    const float* W1  = (const float*)d_in[3];
    const float* b1  = (const float*)d_in[4];
    const float* W2  = (const float*)d_in[5];
    const float* b2  = (const float*)d_in[6];
    float* out = (float*)d_out;

    char* ws = (char*)d_ws;
    unsigned short* vb   = (unsigned short*)ws;                     // 12.8 MB
    unsigned short* qb   = (unsigned short*)(ws + 12800000);        // 12.8 MB
    int*            gcnt = (int*)(ws + 25600000);                   // 1.6 KB
    unsigned int* coarse = (unsigned int*)(ws + 25610240);          // 7.2 MB

    const int* src = ei;
    const int* dst = ei + N_EDGES;

    (void)hipMemsetAsync(gcnt, 0, NBKT * sizeof(int), stream);
    hipLaunchKernelGGL(bin_kernel, dim3(B1), dim3(1024), 0, stream,
                       src, dst, gcnt, coarse);
    hipLaunchKernelGGL(node_kernel, dim3(NB_NODE), dim3(256), 0, stream,
                       x, pos, W1, b1, vb, qb);
    hipLaunchKernelGGL(agg_kernel, dim3(NSB), dim3(256), 0, stream,
                       vb, qb, W2, b2, gcnt, coarse, out);
}